// Round 1
// baseline (1112.933 us; speedup 1.0000x reference)
//
#include <hip/hip_runtime.h>
#include <math.h>

// Problem constants
#define Hdim 1024
#define Bsz  128
#define N3   3072   // 3*H

// ---------------------------------------------------------------------------
// float4 helpers
// ---------------------------------------------------------------------------
__device__ __forceinline__ void fma4(float4& acc, float s, const float4& w) {
    acc.x = fmaf(s, w.x, acc.x);
    acc.y = fmaf(s, w.y, acc.y);
    acc.z = fmaf(s, w.z, acc.z);
    acc.w = fmaf(s, w.w, acc.w);
}

// ---------------------------------------------------------------------------
// Kernel 1/2: fp32 GEMM  out(128 x 3072) = act(A(128 x 1024) @ W(1024 x ldw)[:, :3072] + bias)
// act == 0 : tanh on cols [0,2048), identity on [2048,3072)   (q,k,v from proj)
// act == 1 : sigmoid on all cols                               (i,f,o gates)
// Grid: (48, 8)  block 256.  Each thread: 1 row x 4 cols, K-loop vectorized.
// ---------------------------------------------------------------------------
__global__ __launch_bounds__(256) void gemm_act_kernel(
    const float* __restrict__ A, int lda,
    const float* __restrict__ W, int ldw,
    const float* __restrict__ bias,
    float* __restrict__ out, int act)
{
    const int tid  = threadIdx.x;
    const int cg   = tid & 15;            // 16 col-groups of 4
    const int r    = tid >> 4;            // 16 rows per block
    const int row  = blockIdx.y * 16 + r; // 0..127
    const int col0 = blockIdx.x * 64 + cg * 4;

    const float* a = A + (size_t)row * lda;
    float4 acc = make_float4(0.f, 0.f, 0.f, 0.f);

    for (int kk = 0; kk < 1024; kk += 4) {
        const float4 xv = *(const float4*)(a + kk);
        const float4 w0 = *(const float4*)(W + (size_t)(kk + 0) * ldw + col0);
        const float4 w1 = *(const float4*)(W + (size_t)(kk + 1) * ldw + col0);
        const float4 w2 = *(const float4*)(W + (size_t)(kk + 2) * ldw + col0);
        const float4 w3 = *(const float4*)(W + (size_t)(kk + 3) * ldw + col0);
        fma4(acc, xv.x, w0);
        fma4(acc, xv.y, w1);
        fma4(acc, xv.z, w2);
        fma4(acc, xv.w, w3);
    }

    const float4 bv = *(const float4*)(bias + col0);
    acc.x += bv.x; acc.y += bv.y; acc.z += bv.z; acc.w += bv.w;

    if (act == 0) {
        if (col0 < 2048) {  // q,k -> tanh ; v raw (col0%4==0, split at 2048 is safe)
            acc.x = tanhf(acc.x); acc.y = tanhf(acc.y);
            acc.z = tanhf(acc.z); acc.w = tanhf(acc.w);
        }
    } else {
        acc.x = 1.0f / (1.0f + expf(-acc.x));
        acc.y = 1.0f / (1.0f + expf(-acc.y));
        acc.z = 1.0f / (1.0f + expf(-acc.z));
        acc.w = 1.0f / (1.0f + expf(-acc.w));
    }

    *(float4*)(out + (size_t)row * N3 + col0) = acc;
}

// ---------------------------------------------------------------------------
// Kernel 3: n_new = f*n + i*k  (write to out), denom[b] = max(sum q*n_new, 1e-6)
// Grid: 128 blocks (one per batch), 256 threads, 4 cols/thread.
// ---------------------------------------------------------------------------
__global__ __launch_bounds__(256) void n_denom_kernel(
    const float* __restrict__ p3,   // q|k|v  (128 x 3072)
    const float* __restrict__ G,    // i|f|o  (128 x 3072)
    const float* __restrict__ n_in,
    float* __restrict__ n_out,
    float* __restrict__ denom)
{
    const int b   = blockIdx.x;
    const int tid = threadIdx.x;
    const int c0  = tid * 4;

    const float4 q  = *(const float4*)(p3 + (size_t)b * N3 + c0);
    const float4 kv = *(const float4*)(p3 + (size_t)b * N3 + 1024 + c0);
    const float4 iv = *(const float4*)(G  + (size_t)b * N3 + c0);
    const float4 fv = *(const float4*)(G  + (size_t)b * N3 + 1024 + c0);
    const float4 nv = *(const float4*)(n_in + (size_t)b * Hdim + c0);

    float4 nn;
    nn.x = fmaf(fv.x, nv.x, iv.x * kv.x);
    nn.y = fmaf(fv.y, nv.y, iv.y * kv.y);
    nn.z = fmaf(fv.z, nv.z, iv.z * kv.z);
    nn.w = fmaf(fv.w, nv.w, iv.w * kv.w);
    *(float4*)(n_out + (size_t)b * Hdim + c0) = nn;

    float s = q.x * nn.x + q.y * nn.y + q.z * nn.z + q.w * nn.w;
    // wave (64-lane) butterfly reduce
    #pragma unroll
    for (int off = 32; off > 0; off >>= 1)
        s += __shfl_down(s, off, 64);

    __shared__ float red[4];
    if ((tid & 63) == 0) red[tid >> 6] = s;
    __syncthreads();
    if (tid == 0) {
        float t = red[0] + red[1] + red[2] + red[3];
        denom[b] = fmaxf(t, 1e-6f);
    }
}

// ---------------------------------------------------------------------------
// Kernel 4: the big one.  C_new = f*C + (i*k) (outer) v ; h_part = sum_r q[r]*C_new[r,:]
// Grid: (128 batches, 4 row-chunks of 256), block 256, 4 cols/thread (float4).
// Per-row scalars (f, i*k, q) staged in LDS once per block.
// ---------------------------------------------------------------------------
__global__ __launch_bounds__(256) void c_update_kernel(
    const float* __restrict__ p3,
    const float* __restrict__ G,
    const float* __restrict__ C_in,
    float* __restrict__ C_out,
    float* __restrict__ hpart)   // (4 x 128 x 1024)
{
    const int b   = blockIdx.x;   // 0..127
    const int rc  = blockIdx.y;   // 0..3
    const int tid = threadIdx.x;
    const int c0  = tid * 4;

    __shared__ float lf[256];
    __shared__ float lik[256];
    __shared__ float lq[256];

    const int rr = rc * 256 + tid;
    lf[tid]  = G[(size_t)b * N3 + 1024 + rr];                                  // f
    lik[tid] = G[(size_t)b * N3 + rr] * p3[(size_t)b * N3 + 1024 + rr];        // i*k
    lq[tid]  = p3[(size_t)b * N3 + rr];                                        // q
    __syncthreads();

    const float4 vv = *(const float4*)(p3 + (size_t)b * N3 + 2048 + c0);

    const size_t base = ((size_t)b << 20) + ((size_t)(rc * 256) << 10) + c0;
    const float* cin  = C_in  + base;
    float*       cout = C_out + base;

    float4 h = make_float4(0.f, 0.f, 0.f, 0.f);

    #pragma unroll 4
    for (int r = 0; r < 256; ++r) {
        const float4 cv = *(const float4*)(cin + (size_t)r * Hdim);
        const float f  = lf[r];
        const float ik = lik[r];
        const float q  = lq[r];
        float4 cn;
        cn.x = fmaf(f, cv.x, ik * vv.x);
        cn.y = fmaf(f, cv.y, ik * vv.y);
        cn.z = fmaf(f, cv.z, ik * vv.z);
        cn.w = fmaf(f, cv.w, ik * vv.w);
        *(float4*)(cout + (size_t)r * Hdim) = cn;
        h.x = fmaf(q, cn.x, h.x);
        h.y = fmaf(q, cn.y, h.y);
        h.z = fmaf(q, cn.z, h.z);
        h.w = fmaf(q, cn.w, h.w);
    }

    *(float4*)(hpart + ((size_t)rc * Bsz + b) * Hdim + c0) = h;
}

// ---------------------------------------------------------------------------
// Kernel 5: h_new = o * (sum_rc hpart) / denom[b]
// ---------------------------------------------------------------------------
__global__ __launch_bounds__(256) void h_out_kernel(
    const float* __restrict__ hpart,
    const float* __restrict__ G,
    const float* __restrict__ denom,
    float* __restrict__ h_out)
{
    const int b   = blockIdx.x;
    const int tid = threadIdx.x;
    const int c0  = tid * 4;

    float4 s = make_float4(0.f, 0.f, 0.f, 0.f);
    #pragma unroll
    for (int rc = 0; rc < 4; ++rc) {
        const float4 p = *(const float4*)(hpart + ((size_t)rc * Bsz + b) * Hdim + c0);
        s.x += p.x; s.y += p.y; s.z += p.z; s.w += p.w;
    }
    const float4 o = *(const float4*)(G + (size_t)b * N3 + 2048 + c0);
    const float inv_d = 1.0f / denom[b];
    float4 hn;
    hn.x = o.x * s.x * inv_d;
    hn.y = o.y * s.y * inv_d;
    hn.z = o.z * s.z * inv_d;
    hn.w = o.w * s.w * inv_d;
    *(float4*)(h_out + (size_t)b * Hdim + c0) = hn;
}

// ---------------------------------------------------------------------------
// Launch
// ---------------------------------------------------------------------------
extern "C" void kernel_launch(void* const* d_in, const int* in_sizes, int n_in,
                              void* d_out, int out_size, void* d_ws, size_t ws_size,
                              hipStream_t stream)
{
    const float* x       = (const float*)d_in[0];   // (128,1024)
    const float* C       = (const float*)d_in[1];   // (128,1024,1024)
    const float* n       = (const float*)d_in[2];   // (128,1024)
    // d_in[3] = h : unused by the reference computation
    const float* W_proj  = (const float*)d_in[4];   // (1024,4096)
    const float* b_proj  = (const float*)d_in[5];   // (4096,)
    const float* W_gates = (const float*)d_in[6];   // (1024,3072)
    const float* b_gates = (const float*)d_in[7];   // (3072,)

    float* out   = (float*)d_out;
    float* h_out = out;                               // (128,1024)
    float* C_out = out + 131072;                      // (128,1024,1024)
    float* n_out = out + 131072 + 134217728;          // (128,1024)

    float* ws    = (float*)d_ws;
    float* p3    = ws;                // 128*3072  : q|k|v  (tanh applied to q,k)
    float* G     = ws + 393216;       // 128*3072  : i|f|o  (sigmoid applied)
    float* denom = ws + 786432;       // 128
    float* hpart = ws + 786560;       // 4*128*1024

    // 1) proj -> q,k,v  (only first 3H cols of W_proj; g is dead code)
    gemm_act_kernel<<<dim3(48, 8), 256, 0, stream>>>(x, 1024, W_proj, 4096, b_proj, p3, 0);
    // 2) gates = sigmoid(v @ W_gates + b)
    gemm_act_kernel<<<dim3(48, 8), 256, 0, stream>>>(p3 + 2048, N3, W_gates, N3, b_gates, G, 1);
    // 3) n_new + denom
    n_denom_kernel<<<128, 256, 0, stream>>>(p3, G, n, n_out, denom);
    // 4) C update + retrieval partials
    c_update_kernel<<<dim3(128, 4), 256, 0, stream>>>(p3, G, C, C_out, hpart);
    // 5) h epilogue
    h_out_kernel<<<128, 256, 0, stream>>>(hpart, G, denom, h_out);
}